// Round 1
// 256.231 us; speedup vs baseline: 1.0187x; 1.0187x over previous
//
#include <hip/hip_runtime.h>
#include <hip/hip_bf16.h>

#define B_ 16
#define L_ 1024
#define D_ 768
#define H_ 4
#define C_ 256
#define E_ 8192
#define ET_ (E_ + L_)     // 9216 edges per graph incl. self loops
#define HC_ (H_ * C_)     // 1024
#define F_ (D_ + HC_)     // 1792
#define M_ (B_ * L_)      // 16384 total nodes
#define NEG_SLOPE 0.2f

typedef short bf16x8 __attribute__((ext_vector_type(8)));
typedef float f32x4 __attribute__((ext_vector_type(4)));
using bf16 = __hip_bfloat16;

struct bf16x4_s { bf16 x, y, z, w; };

// ---------------- async global->LDS, 16B per lane ----------------
__device__ __forceinline__ void async_copy16(const bf16* gsrc, bf16* ldst) {
  __builtin_amdgcn_global_load_lds(
      (const __attribute__((address_space(1))) unsigned int*)gsrc,
      (__attribute__((address_space(3))) unsigned int*)ldst, 16, 0, 0);
}

// ============ kernel 1: prep — CSR (LDS) + x cast + weight casts + cout ============
#define NB_CSR 16
#define NB_X (M_ * (D_ / 8) / 256)   // 6144: one 8-elem chunk per thread
#define NB_W 2112                     // (HC_*D_ + D_*F_)/4/256 float4 chunks
#define NB_CO 3

__global__ __launch_bounds__(256)
void prep(const float* __restrict__ x, const int* __restrict__ ei,
          const float* __restrict__ Wg, const float* __restrict__ Wout,
          const float* __restrict__ bgat, const float* __restrict__ bout,
          bf16* __restrict__ xf, bf16* __restrict__ wg_bf, bf16* __restrict__ wout_bf,
          int* __restrict__ deg_g, int* __restrict__ offs_g, int* __restrict__ csr_src,
          float* __restrict__ cout)
{
  __shared__ int s_deg[L_];
  __shared__ int s_cur[L_];
  __shared__ int s_part[256];
  const int blk = blockIdx.x;
  const int t = threadIdx.x;

  if (blk < NB_CSR) {
    // ---- whole CSR for graph b in one block: count -> scan -> fill (LDS only) ----
    const int b = blk;
    const int* srcp = ei + (long)b * 2 * E_;
    const int* dstp = srcp + E_;
    for (int i = t; i < L_; i += 256) s_deg[i] = 0;
    __syncthreads();
    for (int e = t; e < ET_; e += 256) {
      int dst = (e < E_) ? dstp[e] : (e - E_);
      atomicAdd(&s_deg[dst], 1);
    }
    __syncthreads();
    int d0 = s_deg[t*4], d1 = s_deg[t*4+1], d2 = s_deg[t*4+2], d3 = s_deg[t*4+3];
    int tsum = d0 + d1 + d2 + d3;
    s_part[t] = tsum;
    __syncthreads();
    for (int o = 1; o < 256; o <<= 1) {
      int v = (t >= o) ? s_part[t - o] : 0;
      __syncthreads();
      s_part[t] += v;
      __syncthreads();
    }
    int run = s_part[t] - tsum;       // exclusive prefix
    int o0 = run, o1 = o0 + d0, o2 = o1 + d1, o3 = o2 + d2;
    s_cur[t*4] = o0; s_cur[t*4+1] = o1; s_cur[t*4+2] = o2; s_cur[t*4+3] = o3;
    int gb = b * L_ + t * 4;
    offs_g[gb] = o0; offs_g[gb+1] = o1; offs_g[gb+2] = o2; offs_g[gb+3] = o3;
    deg_g[gb] = d0; deg_g[gb+1] = d1; deg_g[gb+2] = d2; deg_g[gb+3] = d3;
    __syncthreads();
    int* csr_b = csr_src + (long)b * ET_;
    for (int e = t; e < ET_; e += 256) {
      int src = (e < E_) ? srcp[e] : (e - E_);
      int dst = (e < E_) ? dstp[e] : (e - E_);
      int slot = atomicAdd(&s_cur[dst], 1);
      csr_b[slot] = src;
    }
  } else if (blk < NB_CSR + NB_X) {
    // ---- x cast: one 8-elem chunk per thread into xf cols 0..767 ----
    int idx = (blk - NB_CSR) * 256 + t;
    int row = idx / (D_ / 8);
    int c8 = idx - row * (D_ / 8);
    const float4* src = (const float4*)(x + (long)row * D_ + c8 * 8);
    float4 v0 = src[0], v1 = src[1];
    bf16 o[8];
    o[0] = __float2bfloat16(v0.x); o[1] = __float2bfloat16(v0.y);
    o[2] = __float2bfloat16(v0.z); o[3] = __float2bfloat16(v0.w);
    o[4] = __float2bfloat16(v1.x); o[5] = __float2bfloat16(v1.y);
    o[6] = __float2bfloat16(v1.z); o[7] = __float2bfloat16(v1.w);
    *(uint4*)(xf + (long)row * F_ + c8 * 8) = *(const uint4*)o;
  } else if (blk < NB_CSR + NB_X + NB_W) {
    // ---- weight casts: Wg then Wout, one float4 per thread ----
    long na4 = (long)HC_ * D_ / 4;
    long nb4 = (long)D_ * F_ / 4;
    long i0 = (long)(blk - NB_CSR - NB_X) * 256 + t;
    long stride = (long)NB_W * 256;
    for (long i = i0; i < na4 + nb4; i += stride) {
      const float4 v = (i < na4) ? ((const float4*)Wg)[i] : ((const float4*)Wout)[i - na4];
      bf16x4_s o;
      o.x = __float2bfloat16(v.x);
      o.y = __float2bfloat16(v.y);
      o.z = __float2bfloat16(v.z);
      o.w = __float2bfloat16(v.w);
      if (i < na4) ((bf16x4_s*)wg_bf)[i] = o;
      else         ((bf16x4_s*)wout_bf)[i - na4] = o;
    }
  } else {
    // ---- cout[o] = b_out[o] + sum_j b_gat[j] * W_out[o, D_+j] ----
    int o = (blk - NB_CSR - NB_X - NB_W) * 256 + t;
    if (o < D_) {
      float s = bout[o];
      const float* wrow = Wout + (long)o * F_ + D_;
      for (int j = 0; j < HC_; j++) s += bgat[j] * wrow[j];
      cout[o] = s;
    }
  }
}

// ============ NT GEMM, 256x256 tile, BK=64, 8-phase counted-vmcnt schedule ============
// Plain-HIP port of the m201 8-phase template (T2+T3+T4+T5):
//  - 512 threads = 8 waves as 2(M)x4(N); per-wave output 128x64; acc[8][4] f32x4.
//  - 16x16x32 bf16 MFMA. A frag: row=lane&15, k=(lane>>4)*8+j; B^T same; C/D (m89):
//    col=lane&15, row=(lane>>4)*4+reg.
//  - LDS 128KB: As[2][256][64] + Bs[2][256][64], XOR 16B-chunk swizzle applied on the
//    GLOBAL source address (global_load_lds writes linearly), compensated at ds_read.
//    With 16-row fragments the ds_read conflict degree is 2-way == free (m136).
//  - 4 quadrant-phases per K-tile (quad order (rh,ch)=(0,0),(0,1),(1,1),(1,0)), 16 MFMA
//    each, raw s_barrier pairs (NO __syncthreads => no forced vmcnt(0) drain).
//  - Staging at quarter granularity (64 rows = 1 global_load_lds per thread):
//      P0: A(g+1) q1,q3   [dest slots last read at prior group's P2/P3 -> free]
//      P1: B(g+1) q0,q1   [B(g-1) fully read by end of prior group]
//      P2: B(g+1) q2,q3
//      P3: A(g+2) q0,q2 into the CURRENT buffer [those rows' ds_reads all issued at P0]
//    => group-boundary wait is s_waitcnt vmcnt(2): queue never drains in steady state.
__global__ __launch_bounds__(512, 2)
void gemm_dummy_decl();   // (keeps section header grep-able)

template <int OUT_BF16>
__global__ __launch_bounds__(512, 2)
void gemm_nt_256(const bf16* __restrict__ A, int lda,
                 const bf16* __restrict__ Bm, int ldb,
                 void* __restrict__ Cm_, int ldc, int K,
                 const float* __restrict__ bias)
{
  __shared__ __align__(16) bf16 As_s[2 * 256 * 64];   // 64 KB
  __shared__ __align__(16) bf16 Bs_s[2 * 256 * 64];   // 64 KB
  const int t = threadIdx.x;
  const int lane = t & 63;
  const int wave = t >> 6;
  const int wrow = wave >> 2;          // 0..1  (M half)
  const int wcol = wave & 3;           // 0..3  (N strip)
  const long m0 = (long)blockIdx.x * 256;
  const long n0 = (long)blockIdx.y * 256;
  const int l15 = lane & 15;
  const int kg = lane >> 4;            // 0..3
  const int NT = K >> 6;               // K-tiles of 64
  const int s_row8 = wave * 8 + (lane >> 3);   // row within a 64-row quarter
  const int s_c8 = lane & 7;

  f32x4 acc[8][4] = {};
  bf16x8 af[4][2], bfr[4][2];

  // stage one quarter (64 rows x 64 k) of A or B for K-tile kt into buffer buf
  auto stA = [&](int buf, int kt, int r0) {
    int lr = r0 + s_row8;
    int cs = s_c8 ^ (lr & 7);
    async_copy16(A + (m0 + lr) * (long)lda + (kt << 6) + (cs << 3),
                 As_s + buf * (256 * 64) + (r0 + wave * 8) * 64);
  };
  auto stB = [&](int buf, int kt, int r0) {
    int lr = r0 + s_row8;
    int cs = s_c8 ^ (lr & 7);
    async_copy16(Bm + (n0 + lr) * (long)ldb + (kt << 6) + (cs << 3),
                 Bs_s + buf * (256 * 64) + (r0 + wave * 8) * 64);
  };

  // ---- prologue: Kt0 fully, plus A(1) q0,q2 (steady-state pattern) ----
  stA(0, 0, 0); stA(0, 0, 64); stA(0, 0, 128); stA(0, 0, 192);
  stB(0, 0, 0); stB(0, 0, 64); stB(0, 0, 128); stB(0, 0, 192);
  if (NT > 1) {
    stA(1, 1, 0); stA(1, 1, 128);
    asm volatile("s_waitcnt vmcnt(2)" ::: "memory");
  } else {
    asm volatile("s_waitcnt vmcnt(0)" ::: "memory");
  }
  __builtin_amdgcn_s_barrier();

  for (int g = 0; g < NT; ++g) {
    const int buf = g & 1;
    const bf16* Ab = As_s + buf * (256 * 64);
    const bf16* Bb = Bs_s + buf * (256 * 64);

    // ---------- P0: quad (rh0, fc 0-1); read A rh0 (8) + B fc0-1 (4) ----------
#pragma unroll
    for (int fr = 0; fr < 4; fr++) {
      int ra = wrow * 128 + fr * 16 + l15;
#pragma unroll
      for (int ks = 0; ks < 2; ks++) {
        int c = ks * 4 + kg;
        af[fr][ks] = *(const bf16x8*)(Ab + ra * 64 + ((c ^ (ra & 7)) << 3));
      }
    }
#pragma unroll
    for (int fc = 0; fc < 2; fc++) {
      int rb = wcol * 64 + fc * 16 + l15;
#pragma unroll
      for (int ks = 0; ks < 2; ks++) {
        int c = ks * 4 + kg;
        bfr[fc][ks] = *(const bf16x8*)(Bb + rb * 64 + ((c ^ (rb & 7)) << 3));
      }
    }
    if (g + 1 < NT) { stA(buf ^ 1, g + 1, 64); stA(buf ^ 1, g + 1, 192); }
    __builtin_amdgcn_s_barrier();
    __builtin_amdgcn_sched_barrier(0);
    __builtin_amdgcn_s_setprio(1);
#pragma unroll
    for (int ks = 0; ks < 2; ks++)
#pragma unroll
      for (int fr = 0; fr < 4; fr++)
#pragma unroll
        for (int fc = 0; fc < 2; fc++)
          acc[fr][fc] = __builtin_amdgcn_mfma_f32_16x16x32_bf16(af[fr][ks], bfr[fc][ks], acc[fr][fc], 0, 0, 0);
    __builtin_amdgcn_s_setprio(0);
    __builtin_amdgcn_sched_barrier(0);
    __builtin_amdgcn_s_barrier();

    // ---------- P1: quad (rh0, fc 2-3); read B fc2-3 (4) ----------
#pragma unroll
    for (int fc = 2; fc < 4; fc++) {
      int rb = wcol * 64 + fc * 16 + l15;
#pragma unroll
      for (int ks = 0; ks < 2; ks++) {
        int c = ks * 4 + kg;
        bfr[fc][ks] = *(const bf16x8*)(Bb + rb * 64 + ((c ^ (rb & 7)) << 3));
      }
    }
    if (g + 1 < NT) { stB(buf ^ 1, g + 1, 0); stB(buf ^ 1, g + 1, 64); }
    __builtin_amdgcn_s_barrier();
    __builtin_amdgcn_sched_barrier(0);
    __builtin_amdgcn_s_setprio(1);
#pragma unroll
    for (int ks = 0; ks < 2; ks++)
#pragma unroll
      for (int fr = 0; fr < 4; fr++)
#pragma unroll
      for (int fc = 2; fc < 4; fc++)
        acc[fr][fc] = __builtin_amdgcn_mfma_f32_16x16x32_bf16(af[fr][ks], bfr[fc][ks], acc[fr][fc], 0, 0, 0);
    __builtin_amdgcn_s_setprio(0);
    __builtin_amdgcn_sched_barrier(0);
    __builtin_amdgcn_s_barrier();

    // ---------- P2: quad (rh1, fc 2-3); read A rh1 (8), overwrite af ----------
#pragma unroll
    for (int fr = 0; fr < 4; fr++) {
      int ra = wrow * 128 + 64 + fr * 16 + l15;
#pragma unroll
      for (int ks = 0; ks < 2; ks++) {
        int c = ks * 4 + kg;
        af[fr][ks] = *(const bf16x8*)(Ab + ra * 64 + ((c ^ (ra & 7)) << 3));
      }
    }
    if (g + 1 < NT) { stB(buf ^ 1, g + 1, 128); stB(buf ^ 1, g + 1, 192); }
    __builtin_amdgcn_s_barrier();
    __builtin_amdgcn_sched_barrier(0);
    __builtin_amdgcn_s_setprio(1);
#pragma unroll
    for (int ks = 0; ks < 2; ks++)
#pragma unroll
      for (int fr = 0; fr < 4; fr++)
#pragma unroll
      for (int fc = 2; fc < 4; fc++)
        acc[4 + fr][fc] = __builtin_amdgcn_mfma_f32_16x16x32_bf16(af[fr][ks], bfr[fc][ks], acc[4 + fr][fc], 0, 0, 0);
    __builtin_amdgcn_s_setprio(0);
    __builtin_amdgcn_sched_barrier(0);
    __builtin_amdgcn_s_barrier();

    // ---------- P3: quad (rh1, fc 0-1); no ds_reads; prefetch A(g+2) q0,q2 into CURRENT buf ----------
    // Safe: rows 0-63 / 128-191 of this buffer had their ds_reads issued only at P0,
    // completed before each wave's P0 MFMAs; all waves are past P2's barrier here.
    if (g + 2 < NT) { stA(buf, g + 2, 0); stA(buf, g + 2, 128); }
    __builtin_amdgcn_s_barrier();
    __builtin_amdgcn_sched_barrier(0);
    __builtin_amdgcn_s_setprio(1);
#pragma unroll
    for (int ks = 0; ks < 2; ks++)
#pragma unroll
      for (int fr = 0; fr < 4; fr++)
#pragma unroll
      for (int fc = 0; fc < 2; fc++)
        acc[4 + fr][fc] = __builtin_amdgcn_mfma_f32_16x16x32_bf16(af[fr][ks], bfr[fc][ks], acc[4 + fr][fc], 0, 0, 0);
    __builtin_amdgcn_s_setprio(0);
    __builtin_amdgcn_sched_barrier(0);
    // ---- group boundary: counted wait — next K-tile landed, 2 newest (A(g+2) q0,q2) may fly ----
    if (g + 2 < NT)      asm volatile("s_waitcnt vmcnt(2)" ::: "memory");
    else if (g + 1 < NT) asm volatile("s_waitcnt vmcnt(0)" ::: "memory");
    __builtin_amdgcn_s_barrier();
  }

  // ---- epilogue: C/D map col=lane&15, row=(lane>>4)*4+reg ----
#pragma unroll
  for (int fr = 0; fr < 8; fr++) {
#pragma unroll
    for (int fc = 0; fc < 4; fc++) {
      long col = n0 + wcol * 64 + fc * 16 + l15;
      float bv = bias ? bias[col] : 0.f;
#pragma unroll
      for (int reg = 0; reg < 4; reg++) {
        long row = m0 + wrow * 128 + fr * 16 + kg * 4 + reg;
        float v = acc[fr][fc][reg] + bv;
        if (OUT_BF16) ((bf16*)Cm_)[row * ldc + col] = __float2bfloat16(v);
        else          ((float*)Cm_)[row * ldc + col] = v;
      }
    }
  }
}

// ============ fused aggregate: one WAVE per (b,dst), single pass ============
__device__ inline float lrelu(float v) { return v > 0.f ? v : NEG_SLOPE * v; }

__device__ __forceinline__ void unpack16(uint4 u0, uint4 u1, float* f) {
#pragma unroll
  for (int k = 0; k < 4; k++) {
    unsigned w = ((const unsigned*)&u0)[k];
    f[2 * k]     = __uint_as_float(w << 16);
    f[2 * k + 1] = __uint_as_float(w & 0xffff0000u);
    unsigned w2 = ((const unsigned*)&u1)[k];
    f[8 + 2 * k]     = __uint_as_float(w2 << 16);
    f[8 + 2 * k + 1] = __uint_as_float(w2 & 0xffff0000u);
  }
}

__global__ __launch_bounds__(256)
void gat_aggregate(const int* __restrict__ offs, const int* __restrict__ deg_a,
                   const int* __restrict__ csr_src,
                   const float* __restrict__ att_s_g, const float* __restrict__ att_d_g,
                   const bf16* __restrict__ h, bf16* __restrict__ xg, int ldx)
{
  const int t = threadIdx.x;
  const int lane = t & 63;
  const int wave = t >> 6;
  // XCD swizzle: graph b pinned to XCD b%8 (2 graphs = 4MB h per XCD L2)
  const int i = blockIdx.x;
  const int b = (i & 7) + 8 * ((i >> 3) >> 8);
  const int grp = (i >> 3) & 255;
  const int bd = b * L_ + grp * 4 + wave;
  const int deg = deg_a[bd];
  const int* list = csr_src + (long)b * ET_ + offs[bd];
  const int c0 = lane * 16;            // my 16 channels; head = lane>>4

  float as16[16], ad16[16];
#pragma unroll
  for (int q = 0; q < 4; q++) {
    *(float4*)(as16 + 4 * q) = *(const float4*)(att_s_g + c0 + 4 * q);
    *(float4*)(ad16 + 4 * q) = *(const float4*)(att_d_g + c0 + 4 * q);
  }

  // dst's own att_dst logit part (uniform within my 16-lane head group after reduce)
  const bf16* hrow_d = h + (long)bd * HC_ + c0;
  float fd[16];
  unpack16(*(const uint4*)hrow_d, *(const uint4*)(hrow_d + 8), fd);
  float ad = 0.f;
#pragma unroll
  for (int k = 0; k < 16; k++) ad += fd[k] * ad16[k];
#pragma unroll
  for (int o = 1; o < 16; o <<= 1) ad += __shfl_xor(ad, o);

  float acc[16];
#pragma unroll
  for (int k = 0; k < 16; k++) acc[k] = 0.f;
  float ssum = 0.f;
  const bf16* hb = h + (long)b * L_ * HC_ + c0;

  if (deg <= 64) {
    int s_lane = (lane < deg) ? list[lane] : 0;
#pragma unroll 2
    for (int e = 0; e < deg; e++) {
      int se = __shfl(s_lane, e);
      const bf16* hp = hb + (long)se * HC_;
      uint4 u0 = *(const uint4*)hp;
      uint4 u1 = *(const uint4*)(hp + 8);
      float f[16];
      unpack16(u0, u1, f);
      float ds = 0.f;
#pragma unroll
      for (int k = 0; k < 16; k++) ds += f[k] * as16[k];
#pragma unroll
      for (int o = 1; o < 16; o <<= 1) ds += __shfl_xor(ds, o);
      float p = __expf(lrelu(ds + ad));
      ssum += p;
#pragma unroll
      for (int k = 0; k < 16; k++) acc[k] += p * f[k];
    }
  } else {
    for (int e = 0; e < deg; e++) {
      int se = list[e];
      const bf16* hp = hb + (long)se * HC_;
      uint4 u0 = *(const uint4*)hp;
      uint4 u1 = *(const uint4*)(hp + 8);
      float f[16];
      unpack16(u0, u1, f);
      float ds = 0.f;
#pragma unroll
      for (int k = 0; k < 16; k++) ds += f[k] * as16[k];
#pragma unroll
      for (int o = 1; o < 16; o <<= 1) ds += __shfl_xor(ds, o);
      float p = __expf(lrelu(ds + ad));
      ssum += p;
#pragma unroll
      for (int k = 0; k < 16; k++) acc[k] += p * f[k];
    }
  }

  float rs = 1.f / (ssum + 1e-16f);
  bf16 ov[16];
#pragma unroll
  for (int k = 0; k < 16; k++) ov[k] = __float2bfloat16(acc[k] * rs);
  bf16* op = xg + (long)bd * ldx + c0;
  *(uint4*)op = *(const uint4*)ov;
  *(uint4*)(op + 8) = *(const uint4*)(ov + 8);
}

// ---------------- launch ----------------
extern "C" void kernel_launch(void* const* d_in, const int* in_sizes, int n_in,
                              void* d_out, int out_size, void* d_ws, size_t ws_size,
                              hipStream_t stream) {
  const float* x     = (const float*)d_in[0];
  const int*   ei    = (const int*)d_in[1];
  const float* Wg    = (const float*)d_in[2];
  const float* att_s = (const float*)d_in[3];
  const float* att_d = (const float*)d_in[4];
  const float* bgat  = (const float*)d_in[5];
  const float* Wout  = (const float*)d_in[6];
  const float* bout  = (const float*)d_in[7];
  float* out = (float*)d_out;

  char* ws = (char*)d_ws;
  size_t off = 0;
  auto alloc = [&](size_t bytes) {
    void* p = ws + off;
    off = (off + bytes + 255) & ~(size_t)255;
    return p;
  };
  bf16* xf      = (bf16*)alloc((size_t)M_ * F_ * 2);       // 56 MB: [x | xg] bf16
  bf16* wg_bf   = (bf16*)alloc((size_t)HC_ * D_ * 2);
  bf16* wout_bf = (bf16*)alloc((size_t)D_ * F_ * 2);
  bf16* h_bf    = (bf16*)alloc((size_t)M_ * HC_ * 2);      // 32 MB
  int* deg      = (int*)alloc((size_t)M_ * 4);
  int* offs     = (int*)alloc((size_t)M_ * 4);
  int* csr_src  = (int*)alloc((size_t)B_ * ET_ * 4);
  float* cout   = (float*)alloc((size_t)D_ * 4);

  // 1. prep: CSR + x cast + weight casts + cout — one dispatch
  prep<<<dim3(NB_CSR + NB_X + NB_W + NB_CO), dim3(256), 0, stream>>>(
      x, ei, Wg, Wout, bgat, bout, xf, wg_bf, wout_bf, deg, offs, csr_src, cout);

  // 2. h = x @ Wg^T (bf16 out) — 64 x 4 = 256 blocks (1/CU), 8-phase schedule
  gemm_nt_256<1><<<dim3(M_ / 256, HC_ / 256), dim3(512), 0, stream>>>(
      xf, F_, wg_bf, D_, h_bf, HC_, D_, nullptr);

  // 3. fused logits + softmax + aggregate (wave per node), writes xg columns of xf
  gat_aggregate<<<dim3(M_ / 4), dim3(256), 0, stream>>>(offs, deg, csr_src,
                                                        att_s, att_d, h_bf, xf + D_, F_);

  // 4. out = [x|xg] @ W_out^T + cout   (single K=1792 GEMM) — 64 x 3 = 192 blocks
  gemm_nt_256<0><<<dim3(M_ / 256, D_ / 256), dim3(512), 0, stream>>>(
      xf, F_, wout_bf, F_, out, D_, F_, cout);
}